// Round 4
// baseline (72.196 us; speedup 1.0000x reference)
//
#include <hip/hip_runtime.h>

// QuanvLayer — closed form via Heisenberg picture. (See round-3 derivation.)
//   out_q = cos(pf_q)<Z_q> - sin(pf_q)<X_q> on the post-CNOT state;
//   CNOT ring conjugated back to the layer-1 PRODUCT state:
//   <Z0>->Z1Z2Z3  <Z1>->Z0Z1  <Z2>->Z0Z1Z2  <Z3>->Z0Z1Z2Z3
//   <X0>->X0X1    <X1>->X1X2  <X2>->X2X3    <X3>->X3X0X1
//   Bloch: z0=cos p0 cos(pi x0), x0=sin(pi x0); z1=cos(pi x1+p1), x1=sin(pi x1+p1);
//          z2=cos(pi x2), x2=cos p2 sin(pi x2); z3=sin(pi x3), x3=cos(pi x3).
// Round 4: 2 patches/thread via two coalesced streams (tid, tid+half) —
// doubles per-thread memory ILP, amortizes the 12 wave-uniform param
// transcendentals over 2 patches. Diagnostic for memory-bound vs issue-bound.

struct PTrig {
    float A, Cp1, Sp1, Bc;
    float Cf0, Sf0, Cf1, Sf1, Cf2, Sf2, Cf3, Sf3;
};

__device__ __forceinline__ float4 quanv_patch(const float4 xv, const PTrig& p) {
    // trig of pi*x_q via hw sin/cos in revolutions: rev = 0.5*x, x in [0,1)
    float c0 = __builtin_amdgcn_cosf(0.5f * xv.x);
    float s0 = __builtin_amdgcn_sinf(0.5f * xv.x);
    float c1 = __builtin_amdgcn_cosf(0.5f * xv.y);
    float s1 = __builtin_amdgcn_sinf(0.5f * xv.y);
    float c2 = __builtin_amdgcn_cosf(0.5f * xv.z);
    float s2 = __builtin_amdgcn_sinf(0.5f * xv.z);
    float c3 = __builtin_amdgcn_cosf(0.5f * xv.w);
    float s3 = __builtin_amdgcn_sinf(0.5f * xv.w);

    // qubit-1 Bloch after RY(p1): angle addition
    float z1 = c1 * p.Cp1 - s1 * p.Sp1;   // cos(pi x1 + p1)
    float x1 = s1 * p.Cp1 + c1 * p.Sp1;   // sin(pi x1 + p1)

    float P = p.A * c0 * z1;              // z0*z1
    float R = P * c2;                     // z0*z1*z2
    float Q = z1 * c2;                    // z1*z2
    float T = s0 * x1;                    // x0*x1
    float W = p.Bc * s2;                  // x2

    float4 o;
    o.x = p.Cf0 * (Q * s3) - p.Sf0 * T;          // z1z2z3 | x0x1
    o.y = p.Cf1 * P        - p.Sf1 * (x1 * W);   // z0z1   | x1x2
    o.z = p.Cf2 * R        - p.Sf2 * (W * c3);   // z0z1z2 | x2x3
    o.w = p.Cf3 * (R * s3) - p.Sf3 * (c3 * T);   // z0..z3 | x3x0x1
    return o;
}

__global__ __launch_bounds__(256) void quanv_kernel(
    const float4* __restrict__ x,   // [N] patches
    const float* __restrict__ prm,  // [7]
    float4* __restrict__ out,       // [N]
    int half)                       // N/2
{
    int tid = blockIdx.x * 256 + threadIdx.x;
    if (tid >= half) return;

    const float INV_2PI = 0.15915494309189535f;
    PTrig p;
    p.A   = __builtin_amdgcn_cosf(prm[0] * INV_2PI);
    p.Cp1 = __builtin_amdgcn_cosf(prm[1] * INV_2PI);
    p.Sp1 = __builtin_amdgcn_sinf(prm[1] * INV_2PI);
    p.Bc  = __builtin_amdgcn_cosf(prm[2] * INV_2PI);
    p.Cf0 = __builtin_amdgcn_cosf(prm[3] * INV_2PI);
    p.Sf0 = __builtin_amdgcn_sinf(prm[3] * INV_2PI);
    p.Cf1 = __builtin_amdgcn_cosf(prm[4] * INV_2PI);
    p.Sf1 = __builtin_amdgcn_sinf(prm[4] * INV_2PI);
    p.Cf2 = __builtin_amdgcn_cosf(prm[5] * INV_2PI);
    p.Sf2 = __builtin_amdgcn_sinf(prm[5] * INV_2PI);
    p.Cf3 = __builtin_amdgcn_cosf(prm[6] * INV_2PI);
    p.Sf3 = __builtin_amdgcn_sinf(prm[6] * INV_2PI);

    // two independent coalesced streams -> 2x memory ILP per thread
    const float4 xa = x[tid];
    const float4 xb = x[tid + half];
    float4 oa = quanv_patch(xa, p);
    float4 ob = quanv_patch(xb, p);
    out[tid]        = oa;
    out[tid + half] = ob;
}

extern "C" void kernel_launch(void* const* d_in, const int* in_sizes, int n_in,
                              void* d_out, int out_size, void* d_ws, size_t ws_size,
                              hipStream_t stream) {
    const float4* x  = (const float4*)d_in[0];  // [1204224] float4 patches
    const float* prm = (const float*)d_in[1];   // [7] f32
    float4* out = (float4*)d_out;               // [1204224] float4
    int n = in_sizes[0] / 4;                    // 1,204,224 (even)
    int half = n / 2;                           // 602,112 = 2352 * 256
    int blocks = (half + 255) / 256;            // 2352
    quanv_kernel<<<blocks, 256, 0, stream>>>(x, prm, out, half);
}